// Round 12
// baseline (13863.544 us; speedup 1.0000x reference)
//
#include <hip/hip_runtime.h>

// Echo-state RNN, B=32, T=2048, NH=512.  W_hh ~90% exact zeros.
// r11 post-mortem: SQ_LDS_BANK_CONFLICT ~= gather-instr count (free 2-way
// full-wave aliasing artifact); real conflicts ~0 already. Cost = gather
// INSTRUCTION count (~768/step) x ~3.2cyc LDS issue + ~400cyc tail. And the
// per-half bank-degree floor (avg lane deg, 32 lanes vs 32 banks) means
// slots/wave can't compact below ~90 for one-row-per-thread.
// NEW: 2 rows/thread, 256 threads (4 waves = 1/SIMD -> 512-reg budget).
// Thread t owns rows perm[w*64+l] (seg A) and perm[(7-w)*64+l] (seg B);
// the two scheduled segments concatenate -> ~540 gathers/step (1.4x fewer).
// Seg slots 0..95 pinned in VGPRs, 96..191 in AGPRs (unified file).
// Scheduler: r11 first-fit + ballot-transposed occ build (kills the ~700us
// strided-load preproc cost).

#define NH   512
#define TT   2048
#define BB   32
#define SPAD 96          // scheduler slots per virtual wave
#define PAD2 192         // concatenated per-thread slots (hard bound 96+96)
#define NONE_ 0xFF

// ---------------------------------------------------------------------------
// A: nnz per row (wave-per-row ballot count)
// ---------------------------------------------------------------------------
__global__ __launch_bounds__(512) void count_nnz(
    const float* __restrict__ Whh, int* __restrict__ nnz) {
  const int wib  = threadIdx.x >> 6;
  const int lane = threadIdx.x & 63;
  const int row  = blockIdx.x * 8 + wib;
  const float* wrow = Whh + (size_t)row * NH;
  int cnt = 0;
  for (int c = 0; c < NH / 64; ++c)
    cnt += __popcll(__ballot(wrow[c * 64 + lane] != 0.0f));
  if (lane == 0) nnz[row] = cnt;
}

// ---------------------------------------------------------------------------
// B: rank rows by nnz descending (stable). perm[p] = row at sorted pos p.
// ---------------------------------------------------------------------------
__global__ __launch_bounds__(512) void sort_rows(
    const int* __restrict__ nnz, int* __restrict__ perm) {
  __shared__ int nl[NH];
  const int j = threadIdx.x;
  const int my = nnz[j];
  nl[j] = my;
  __syncthreads();
  int r = 0;
  const int4* p4 = (const int4*)nl;
  for (int i = 0; i < NH / 4; ++i) {
    int4 v = p4[i];
    const int base = i * 4;
    r += (v.x > my) || (v.x == my && base + 0 < j);
    r += (v.y > my) || (v.y == my && base + 1 < j);
    r += (v.z > my) || (v.z == my && base + 2 < j);
    r += (v.w > my) || (v.w == my && base + 3 < j);
  }
  perm[r] = j;
}

// ---------------------------------------------------------------------------
// C: first-fit edge coloring per (virtual wave, half). Block = wave g
// (grid 8, 64 thr). occ built via coalesced loads + ballot transpose.
// ---------------------------------------------------------------------------
__global__ __launch_bounds__(64) void build_sched(
    const float* __restrict__ Whh, const int* __restrict__ perm,
    float* __restrict__ vals, unsigned* __restrict__ offs,
    int* __restrict__ cntw) {
  __shared__ unsigned short occ[64][32];     // [row-in-block][bank] bits
  __shared__ unsigned char  sb[64][SPAD];    // slot -> bank (or NONE_)
  __shared__ unsigned freeL[2][32][3];       // 96-bit free-color masks
  __shared__ unsigned freeB[2][32][3];
  __shared__ int cwsh;

  const int lane = threadIdx.x;
  const int g    = blockIdx.x;
  const int p    = g * 64 + lane;
  const int hl   = lane >> 5;
  const int li   = lane & 31;
  const int row  = perm[p];
  const float* wrow = Whh + (size_t)row * NH;

  if (lane == 0) cwsh = 0;

  // cooperative occ build: per row, 8 coalesced ballots; lane b (<32)
  // assembles bank b's 16-bit presence mask. col = c*64+ln: bank = ln&31,
  // m = 2c + (ln>>5).
  for (int r = 0; r < 64; ++r) {
    const int rw = perm[g * 64 + r];
    const float* wr = Whh + (size_t)rw * NH;
    unsigned m16 = 0;
    for (int c = 0; c < 8; ++c) {
      unsigned long long bal = __ballot(wr[c * 64 + lane] != 0.0f);
      if (lane < 32) {
        m16 |= ((unsigned)((bal >> lane) & 1ull)) << (2 * c);
        m16 |= ((unsigned)((bal >> (lane + 32)) & 1ull)) << (2 * c + 1);
      }
    }
    if (lane < 32) occ[r][lane] = (unsigned short)m16;
  }
  for (int c = 0; c < SPAD; ++c) sb[lane][c] = NONE_;
  #pragma unroll
  for (int w2 = 0; w2 < 3; ++w2) {
    freeL[hl][li][w2] = 0xFFFFFFFFu;
    freeB[hl][li][w2] = 0xFFFFFFFFu;
  }
  __syncthreads();

  if (li == 0) {                             // workers: lanes 0 and 32
    int maxc = 0;
    for (int l = 0; l < 32; ++l) {
      const int gl = hl * 32 + l;
      for (int b = 0; b < 32; ++b) {
        const int mult = __popc((unsigned)occ[gl][b]);
        for (int m = 0; m < mult; ++m) {
          int c = -1;
          #pragma unroll
          for (int w2 = 0; w2 < 3; ++w2) {
            unsigned cm = freeL[hl][l][w2] & freeB[hl][b][w2];
            if (cm) { c = w2 * 32 + __ffs(cm) - 1; break; }
          }
          const bool common = (c >= 0);
          if (!common) {                     // rare: accept one conflict
            #pragma unroll
            for (int w2 = 0; w2 < 3; ++w2) {
              unsigned lm = freeL[hl][l][w2];
              if (c < 0 && lm) c = w2 * 32 + __ffs(lm) - 1;
            }
          }
          sb[gl][c] = (unsigned char)b;
          freeL[hl][l][c >> 5] &= ~(1u << (c & 31));
          if (common) freeB[hl][b][c >> 5] &= ~(1u << (c & 31));
          if (c > maxc) maxc = c;
        }
      }
    }
    atomicMax(&cwsh, maxc + 1);
  }
  __syncthreads();
  if (lane == 0) cntw[g] = cwsh;

  // write phase: slot c -> consume lowest remaining column of matched bank.
  for (int c = 0; c < SPAD; ++c) {
    int b = sb[lane][c];
    float v = 0.f; unsigned col = 0u;
    if (b != NONE_) {
      unsigned m16 = (unsigned)occ[lane][b];
      int m = __ffs(m16) - 1;
      occ[lane][b] = (unsigned short)(m16 & (m16 - 1u));
      col = (unsigned)(b + 32 * m);
      v = wrow[col];
    }
    vals[c * NH + p] = v;
    offs[c * NH + p] = col;
  }
}

// ---------------------------------------------------------------------------
// DPP wave-64 sum reduction on the VALU pipe; lane 63 ends with the full sum.
// ---------------------------------------------------------------------------
template <int CTRL, int RM>
__device__ __forceinline__ float dppadd(float v) {
  int t = __builtin_amdgcn_update_dpp(0, __float_as_int(v), CTRL, RM, 0xF, true);
  return v + __int_as_float(t);
}
__device__ __forceinline__ float wave_sum_lane63(float v) {
  v = dppadd<0xB1,  0xF>(v);
  v = dppadd<0x4E,  0xF>(v);
  v = dppadd<0x141, 0xF>(v);
  v = dppadd<0x140, 0xF>(v);
  v = dppadd<0x142, 0xA>(v);
  v = dppadd<0x143, 0xC>(v);
  return v;
}

// fast tanh: (t-1)/(t+1), t = exp(2x), clamp |x|<=9.
__device__ __forceinline__ float ftanh(float x) {
  float xc = fminf(9.0f, fmaxf(-9.0f, x));
  float t  = __expf(2.0f * xc);
  return (t - 1.0f) * __builtin_amdgcn_rcpf(t + 1.0f);
}

// ---------------------------------------------------------------------------
// Main: one block per batch, 256 threads (4 waves), 2 rows per thread.
// Thread (w,l): row A at sorted pos w*64+l, row B at (7-w)*64+l.
// Slots [0,cAr) gather for A, [cAr,cAr+cBr) for B; both wave-uniform and
// 4-aligned so chunk guards are scalar branches, never straddling.
// ---------------------------------------------------------------------------
#define GA(T_RD, E) (*(const float*)((const char*)(T_RD) + cidx[E]))

#define ESN_STEP(T_RD, T_WR, RWR, SIDX)                                      \
  {                                                                          \
    float a0 = 0.f, a1 = 0.f, b0 = 0.f, b1 = 0.f;                            \
    _Pragma("unroll")                                                        \
    for (int e = 0; e < PAD2; e += 4) {                                      \
      if (e < cAr) {                                                         \
        a0 = fmaf(wval[e + 0], GA(T_RD, e + 0), a0);                         \
        a1 = fmaf(wval[e + 1], GA(T_RD, e + 1), a1);                         \
        a0 = fmaf(wval[e + 2], GA(T_RD, e + 2), a0);                         \
        a1 = fmaf(wval[e + 3], GA(T_RD, e + 3), a1);                         \
      } else if (e < cw) {                                                   \
        b0 = fmaf(wval[e + 0], GA(T_RD, e + 0), b0);                         \
        b1 = fmaf(wval[e + 1], GA(T_RD, e + 1), b1);                         \
        b0 = fmaf(wval[e + 2], GA(T_RD, e + 2), b0);                         \
        b1 = fmaf(wval[e + 3], GA(T_RD, e + 3), b1);                         \
      }                                                                      \
    }                                                                        \
    float dotA = a0 + a1, dotB = b0 + b1;                                    \
    float xv   = x_lds[SIDX];                                                \
    float dhA  = ((dotA - hA) + xv * wihA) + z_prev * wzhA;                  \
    float dhB  = ((dotB - hB) + xv * wihB) + z_prev * wzhB;                  \
    float hAn  = hA + 0.1f * dhA;                                            \
    float hBn  = hB + 0.1f * dhB;                                            \
    float tA   = ftanh(hAn);                                                 \
    float tB   = ftanh(hBn);                                                 \
    T_WR[rowA] = tA;                                                         \
    T_WR[rowB] = tB;                                                         \
    oh[(SIDX) * NH + rowA] = hAn;                                            \
    oh[(SIDX) * NH + rowB] = hBn;                                            \
    float pzs = wave_sum_lane63(fmaf(tA, whzA, tB * whzB));                  \
    if (lane == 63) red[RWR][w] = pzs;                                       \
    asm volatile("s_waitcnt lgkmcnt(0)\n\ts_barrier" ::: "memory");          \
    float4 r4 = *(const float4*)&red[RWR][0];                                \
    float z = (r4.x + r4.y) + (r4.z + r4.w);                                 \
    if (tid == 0) oz[SIDX] = z;                                              \
    z_prev = z; hA = hAn; hB = hBn;                                          \
  }

__global__ __launch_bounds__(256, 1) void esn_steps(
    const float* __restrict__ x,   const float* __restrict__ h0,
    const float* __restrict__ Wih, const float* __restrict__ Whz,
    const float* __restrict__ Wzh, const float* __restrict__ vals,
    const unsigned* __restrict__ offs, const int* __restrict__ perm,
    const int* __restrict__ cntw, float* __restrict__ out) {
  __shared__ float t_lds[2][NH];              // tanh(h), double-buffered
  __shared__ float x_lds[TT];                 // this batch's input row
  __shared__ __align__(16) float red[2][4];   // per-wave z partials

  const int tid  = threadIdx.x;
  const int w    = tid >> 6;                  // wave 0..3
  const int lane = tid & 63;
  const int b    = blockIdx.x;
  const int pA   = w * 64 + lane;             // virtual wave w
  const int pB   = (7 - w) * 64 + lane;       // virtual wave 7-w
  const int rowA = perm[pA];
  const int rowB = perm[pB];

  float* t0 = t_lds[0];
  float* t1 = t_lds[1];

  for (int i = tid; i < TT; i += 256) x_lds[i] = x[(size_t)b * TT + i];

  const int cAr = __builtin_amdgcn_readfirstlane((cntw[w] + 3) & ~3);
  const int cBr = __builtin_amdgcn_readfirstlane((cntw[7 - w] + 3) & ~3);
  const int cw  = cAr + cBr;                  // <= 192 = PAD2 by construction

  // concatenated scheduled entries -> registers. Byte offsets so each
  // gather is a single ds_read with the buffer base folded into the imm.
  float    wval[PAD2];
  unsigned cidx[PAD2];
  #pragma unroll
  for (int e = 0; e < PAD2; ++e) {
    float v = 0.f; unsigned cx = 0u;
    if (e < cAr) {
      v  = vals[e * NH + pA];
      cx = offs[e * NH + pA] * 4u;
    } else if (e < cw) {
      v  = vals[(e - cAr) * NH + pB];
      cx = offs[(e - cAr) * NH + pB] * 4u;
    }
    wval[e] = v; cidx[e] = cx;
  }
  // residency pins: slots 0..95 in arch VGPRs, 96..191 in AGPRs (unified
  // file, 1 wave/SIMD -> 512-reg budget; m08: no spill through ~450).
  #pragma unroll
  for (int e = 0; e < 96; ++e)
    asm volatile("" : "+v"(wval[e]), "+v"(cidx[e]));
  #pragma unroll
  for (int e = 96; e < PAD2; ++e)
    asm volatile("" : "+a"(wval[e]), "+a"(cidx[e]));

  const float wihA = Wih[rowA], wihB = Wih[rowB];
  const float whzA = Whz[rowA], whzB = Whz[rowB];
  const float wzhA = Wzh[rowA], wzhB = Wzh[rowB];
  float hA = h0[(size_t)b * NH + rowA];
  float hB = h0[(size_t)b * NH + rowB];
  float z_prev;

  float* oz = out + (size_t)b * TT;                        // z region [B,T,1]
  float* oh = out + (size_t)BB * TT + (size_t)b * TT * NH; // h region [B,T,NH]

  // ---- init: t0 = tanh(h0); z_prev = sum(tanh(h0) * Whz) ----
  {
    float tA0 = ftanh(hA), tB0 = ftanh(hB);
    t0[rowA] = tA0; t0[rowB] = tB0;
    float pz = wave_sum_lane63(fmaf(tA0, whzA, tB0 * whzB));
    if (lane == 63) red[0][w] = pz;
    __syncthreads();
    float4 r4 = *(const float4*)&red[0][0];
    z_prev = (r4.x + r4.y) + (r4.z + r4.w);
  }

  // ---- 2048 sequential steps, x2 unrolled (constant buffer ptr per body) ----
  for (int s = 0; s < TT; s += 2) {
    ESN_STEP(t0, t1, 1, s);
    ESN_STEP(t1, t0, 0, s + 1);
  }
}

// ---------------------------------------------------------------------------
extern "C" void kernel_launch(void* const* d_in, const int* in_sizes, int n_in,
                              void* d_out, int out_size, void* d_ws,
                              size_t ws_size, hipStream_t stream) {
  const float* x   = (const float*)d_in[0];
  const float* h0  = (const float*)d_in[1];
  const float* Wih = (const float*)d_in[2];
  const float* Whh = (const float*)d_in[3];
  const float* Whz = (const float*)d_in[4];
  const float* Wzh = (const float*)d_in[5];
  float* out = (float*)d_out;

  float*    vals = (float*)d_ws;                     // SPAD*NH f32 = 192 KB
  unsigned* offs = (unsigned*)(vals + SPAD * NH);    // SPAD*NH u32 = 192 KB
  int*      nnz  = (int*)(offs + SPAD * NH);         // NH
  int*      perm = nnz + NH;                         // NH
  int*      cntw = perm + NH;                        // 8

  hipLaunchKernelGGL(count_nnz, dim3(NH / 8), dim3(512), 0, stream, Whh, nnz);
  hipLaunchKernelGGL(sort_rows, dim3(1), dim3(512), 0, stream, nnz, perm);
  hipLaunchKernelGGL(build_sched, dim3(8), dim3(64), 0, stream,
                     Whh, perm, vals, offs, cntw);
  hipLaunchKernelGGL(esn_steps, dim3(BB), dim3(256), 0, stream,
                     x, h0, Wih, Whz, Wzh, vals, offs, perm, cntw, out);
}

// Round 13
// 3868.564 us; speedup vs baseline: 3.5836x; 3.5836x over previous
//
#include <hip/hip_runtime.h>

// Echo-state RNN, B=32, T=2048, NH=512.  W_hh ~90% exact zeros.
// One workgroup (CU) per batch; thread p owns row perm2[p]. Cost model
// (fits r1-r12): step time ~= gather-instrs x 3cyc + 500cyc tail. All prior
// schedulers were GREEDY edge coloring (needs up to 2*Delta-1 colors ->
// cntw ~96). This round: true KOENIG Delta-edge-coloring per (wave, half)
// [chain rule: leave banks via color a, leave lanes via color b -- simple
// path, provably avoids lane l] + a bank-balancing partition of each wave's
// 64 rows between its two halves (flattens half-bank degree peaks).
// Sum cntw ~450 vs 768. esn_steps = round-7 kernel verbatim (best: 2406us;
// r12's 2-row/thread needed 384 regs > 256 cap and spilled catastrophically).

#define NH   512
#define TT   2048
#define BB   32
#define PAD  96
#define PIN  80
#define NONE_ 0xFF

// ---------------------------------------------------------------------------
// A: nnz per row (wave-per-row ballot count)
// ---------------------------------------------------------------------------
__global__ __launch_bounds__(512) void count_nnz(
    const float* __restrict__ Whh, int* __restrict__ nnz) {
  const int wib  = threadIdx.x >> 6;
  const int lane = threadIdx.x & 63;
  const int row  = blockIdx.x * 8 + wib;
  const float* wrow = Whh + (size_t)row * NH;
  int cnt = 0;
  for (int c = 0; c < NH / 64; ++c)
    cnt += __popcll(__ballot(wrow[c * 64 + lane] != 0.0f));
  if (lane == 0) nnz[row] = cnt;
}

// ---------------------------------------------------------------------------
// B: rank rows by nnz descending (stable). perm[p] = row at sorted pos p.
// ---------------------------------------------------------------------------
__global__ __launch_bounds__(512) void sort_rows(
    const int* __restrict__ nnz, int* __restrict__ perm) {
  __shared__ int nl[NH];
  const int j = threadIdx.x;
  const int my = nnz[j];
  nl[j] = my;
  __syncthreads();
  int r = 0;
  const int4* p4 = (const int4*)nl;
  for (int i = 0; i < NH / 4; ++i) {
    int4 v = p4[i];
    const int base = i * 4;
    r += (v.x > my) || (v.x == my && base + 0 < j);
    r += (v.y > my) || (v.y == my && base + 1 < j);
    r += (v.z > my) || (v.z == my && base + 2 < j);
    r += (v.w > my) || (v.w == my && base + 3 < j);
  }
  perm[r] = j;
}

// ---------------------------------------------------------------------------
// C: partition + Koenig Delta-edge-coloring per (wave, half).
// Block = wave g (grid 8, 64 threads). Phases:
//  1. ballot-transposed occ build (occ0 by original desc-nnz order)
//  2. worker lane 0: greedy min-max partition of 64 rows -> 2 halves of 32
//     (balances per-half bank degrees); lorder = new lane -> orig index
//  3. workers lanes 0,32: Koenig insert per edge: lowest common free color
//     under DCAP, else chain-swap (colors a at banks / be at lanes) then
//     place at a. Collision-guarded placement keeps the schedule VALID even
//     if bookkeeping drifts (degrades to a conflict, never wrong results).
//  4. all lanes: write vals/offs entry-major by new position.
// ---------------------------------------------------------------------------
__global__ __launch_bounds__(64) void build_koenig(
    const float* __restrict__ Whh, const int* __restrict__ perm,
    int* __restrict__ perm2, float* __restrict__ vals,
    unsigned* __restrict__ offs, int* __restrict__ cntw) {
  __shared__ unsigned short occ0[64][32];   // by original order
  __shared__ unsigned short occ[64][32];    // by new lane order
  __shared__ unsigned char  mL[2][32][PAD]; // lane-slot -> bank (NONE_)
  __shared__ unsigned char  mB[2][32][PAD]; // bank-slot -> lane (NONE_)
  __shared__ unsigned freeL[2][32][3];      // free-color bitmasks
  __shared__ unsigned freeB[2][32][3];
  __shared__ unsigned char eBk[2][68], eLn[2][68], eCl[2][68];
  __shared__ unsigned char asg[64], lorder[64];
  __shared__ int bl[2][32];
  __shared__ int dcap[2], cmax[2];

  const int lane = threadIdx.x;
  const int g    = blockIdx.x;
  const int hl   = lane >> 5;
  const int li   = lane & 31;

  // -- phase 1: occ0 via coalesced loads + ballot transpose --
  for (int r = 0; r < 64; ++r) {
    const int rw = perm[g * 64 + r];
    const float* wr = Whh + (size_t)rw * NH;
    unsigned m16 = 0;
    for (int c = 0; c < 8; ++c) {
      unsigned long long bal = __ballot(wr[c * 64 + lane] != 0.0f);
      if (lane < 32) {
        m16 |= ((unsigned)((bal >> lane) & 1ull)) << (2 * c);
        m16 |= ((unsigned)((bal >> (lane + 32)) & 1ull)) << (2 * c + 1);
      }
    }
    if (lane < 32) occ0[r][lane] = (unsigned short)m16;
  }
  __syncthreads();

  // -- phase 2: partition (worker = lane 0) --
  if (lane == 0) {
    int cnt0 = 0, cnt1 = 0, lmax0 = 0, lmax1 = 0;
    for (int b = 0; b < 32; ++b) { bl[0][b] = 0; bl[1][b] = 0; }
    for (int r = 0; r < 64; ++r) {
      int m0 = 0, m1 = 0, deg = 0;
      for (int b = 0; b < 32; ++b) {
        int c = __popc((unsigned)occ0[r][b]);
        deg += c;
        int t0 = bl[0][b] + c; if (t0 > m0) m0 = t0;
        int t1 = bl[1][b] + c; if (t1 > m1) m1 = t1;
      }
      int h;
      if (cnt0 >= 32) h = 1;
      else if (cnt1 >= 32) h = 0;
      else h = (m1 < m0) ? 1 : 0;
      asg[r] = (unsigned char)h;
      if (h == 0) ++cnt0; else ++cnt1;
      for (int b = 0; b < 32; ++b) bl[h][b] += __popc((unsigned)occ0[r][b]);
      if (h == 0) { if (deg > lmax0) lmax0 = deg; }
      else        { if (deg > lmax1) lmax1 = deg; }
    }
    int i0 = 0, i1 = 32;
    for (int r = 0; r < 64; ++r) {
      if (asg[r] == 0) lorder[i0++] = (unsigned char)r;
      else             lorder[i1++] = (unsigned char)r;
    }
    int bm0 = 0, bm1 = 0;
    for (int b = 0; b < 32; ++b) {
      if (bl[0][b] > bm0) bm0 = bl[0][b];
      if (bl[1][b] > bm1) bm1 = bl[1][b];
    }
    int d0 = lmax0 > bm0 ? lmax0 : bm0;
    int d1 = lmax1 > bm1 ? lmax1 : bm1;
    dcap[0] = d0 > PAD ? PAD : d0;
    dcap[1] = d1 > PAD ? PAD : d1;
    cmax[0] = 0; cmax[1] = 0;
  }
  __syncthreads();

  // reorder into new lane space; init matching state
  const int lo   = lorder[lane];
  const int row2 = perm[g * 64 + lo];
  perm2[g * 64 + lane] = row2;
  for (int b = 0; b < 32; ++b) occ[lane][b] = occ0[lo][b];
  for (int c = 0; c < PAD; ++c) { mL[hl][li][c] = NONE_; mB[hl][li][c] = NONE_; }
  #pragma unroll
  for (int w2 = 0; w2 < 3; ++w2) {
    freeL[hl][li][w2] = 0xFFFFFFFFu;
    freeB[hl][li][w2] = 0xFFFFFFFFu;
  }
  __syncthreads();

  // -- phase 3: Koenig workers (lanes 0 and 32) --
  if (li == 0) {
    const int DC = dcap[hl];
    unsigned dcm[3];
    for (int w2 = 0; w2 < 3; ++w2) {
      int lobit = w2 * 32, hibit = lobit + 31;
      if (DC <= lobit)      dcm[w2] = 0u;
      else if (DC > hibit)  dcm[w2] = 0xFFFFFFFFu;
      else                  dcm[w2] = (1u << (DC - lobit)) - 1u;
    }
    int maxc = 0;

    for (int l = 0; l < 32; ++l) {
      for (int b = 0; b < 32; ++b) {
        const int mult = __popc((unsigned)occ[hl * 32 + l][b]);
        for (int m = 0; m < mult; ++m) {
          // direct: lowest color free at both endpoints (under DCAP)
          int c = -1;
          #pragma unroll
          for (int w2 = 0; w2 < 3; ++w2) {
            unsigned cm = freeL[hl][l][w2] & freeB[hl][b][w2] & dcm[w2];
            if (cm && c < 0) c = w2 * 32 + __ffs(cm) - 1;
          }
          if (c < 0) {
            // a = lowest free at l, be = lowest free at b (both < DC)
            int a = -1, be = -1;
            #pragma unroll
            for (int w2 = 0; w2 < 3; ++w2) {
              unsigned fm = freeL[hl][l][w2] & dcm[w2];
              if (fm && a < 0) a = w2 * 32 + __ffs(fm) - 1;
              unsigned gm = freeB[hl][b][w2] & dcm[w2];
              if (gm && be < 0) be = w2 * 32 + __ffs(gm) - 1;
            }
            if (a < 0 || be < 0) {
              // pathological: place at any lane-free slot (conflict ok)
              for (int cc = 0; cc < PAD && c < 0; ++cc)
                if (mL[hl][l][cc] == NONE_) c = cc;
            } else {
              // chain: from b leave banks via a, leave lanes via be
              int n = 0, curB = b;
              while (n < 66) {
                int L1 = mB[hl][curB][a];
                if (L1 == NONE_) break;
                eBk[hl][n] = (unsigned char)curB;
                eLn[hl][n] = (unsigned char)L1;
                eCl[hl][n] = (unsigned char)a;  ++n;
                int B1 = mL[hl][L1][be];
                if (B1 == NONE_) break;
                eBk[hl][n] = (unsigned char)B1;
                eLn[hl][n] = (unsigned char)L1;
                eCl[hl][n] = (unsigned char)be; ++n;
                curB = B1;
              }
              for (int i = 0; i < n; ++i) {        // clear pass
                mB[hl][eBk[hl][i]][eCl[hl][i]] = NONE_;
                mL[hl][eLn[hl][i]][eCl[hl][i]] = NONE_;
              }
              for (int i = 0; i < n; ++i) {        // set pass (swapped)
                int nc = (eCl[hl][i] == a) ? be : a;
                mB[hl][eBk[hl][i]][nc] = eLn[hl][i];
                mL[hl][eLn[hl][i]][nc] = eBk[hl][i];
              }
              // refresh free bits for colors a,be at touched nodes
              {
                unsigned am = 1u << (a & 31), bm = 1u << (be & 31);
                int aw = a >> 5, bw = be >> 5;
                // bank b (chain start)
                freeB[hl][b][aw] = (mB[hl][b][a] == NONE_)
                    ? (freeB[hl][b][aw] | am) : (freeB[hl][b][aw] & ~am);
                freeB[hl][b][bw] = (mB[hl][b][be] == NONE_)
                    ? (freeB[hl][b][bw] | bm) : (freeB[hl][b][bw] & ~bm);
                for (int i = 0; i < n; ++i) {
                  int B = eBk[hl][i], L = eLn[hl][i];
                  freeB[hl][B][aw] = (mB[hl][B][a] == NONE_)
                      ? (freeB[hl][B][aw] | am) : (freeB[hl][B][aw] & ~am);
                  freeB[hl][B][bw] = (mB[hl][B][be] == NONE_)
                      ? (freeB[hl][B][bw] | bm) : (freeB[hl][B][bw] & ~bm);
                  freeL[hl][L][aw] = (mL[hl][L][a] == NONE_)
                      ? (freeL[hl][L][aw] | am) : (freeL[hl][L][aw] & ~am);
                  freeL[hl][L][bw] = (mL[hl][L][be] == NONE_)
                      ? (freeL[hl][L][bw] | bm) : (freeL[hl][L][bw] & ~bm);
                }
              }
              c = a;
            }
          }
          // collision-guarded placement (validity net)
          if (c < 0 || mL[hl][l][c] != NONE_) {
            c = -1;
            for (int cc = 0; cc < PAD && c < 0; ++cc)
              if (mL[hl][l][cc] == NONE_) c = cc;
          }
          mL[hl][l][c] = (unsigned char)b;
          freeL[hl][l][c >> 5] &= ~(1u << (c & 31));
          if (mB[hl][b][c] == NONE_) {
            mB[hl][b][c] = (unsigned char)l;
            freeB[hl][b][c >> 5] &= ~(1u << (c & 31));
          }
          if (c > maxc) maxc = c;
        }
      }
    }
    cmax[hl] = maxc + 1;
  }
  __syncthreads();
  if (lane == 0)
    cntw[g] = cmax[0] > cmax[1] ? cmax[0] : cmax[1];

  // -- phase 4: write schedule (entry-major by new position) --
  const float* wr2 = Whh + (size_t)row2 * NH;
  const int p2 = g * 64 + lane;
  for (int c = 0; c < PAD; ++c) {
    int b = mL[hl][li][c];
    float v = 0.f; unsigned col = 0u;
    if (b != NONE_) {
      unsigned m16 = (unsigned)occ[lane][b];
      int m = __ffs(m16) - 1;
      occ[lane][b] = (unsigned short)(m16 & (m16 - 1u));
      col = (unsigned)(b + 32 * m);
      v = wr2[col];
    }
    vals[c * NH + p2] = v;
    offs[c * NH + p2] = col;
  }
}

// ---------------------------------------------------------------------------
// DPP wave-64 sum reduction on the VALU pipe; lane 63 ends with the full sum.
// ---------------------------------------------------------------------------
template <int CTRL, int RM>
__device__ __forceinline__ float dppadd(float v) {
  int t = __builtin_amdgcn_update_dpp(0, __float_as_int(v), CTRL, RM, 0xF, true);
  return v + __int_as_float(t);
}
__device__ __forceinline__ float wave_sum_lane63(float v) {
  v = dppadd<0xB1,  0xF>(v);
  v = dppadd<0x4E,  0xF>(v);
  v = dppadd<0x141, 0xF>(v);
  v = dppadd<0x140, 0xF>(v);
  v = dppadd<0x142, 0xA>(v);
  v = dppadd<0x143, 0xC>(v);
  return v;
}

// fast tanh: (t-1)/(t+1), t = exp(2x), clamp |x|<=9.
__device__ __forceinline__ float ftanh(float x) {
  float xc = fminf(9.0f, fmaxf(-9.0f, x));
  float t  = __expf(2.0f * xc);
  return (t - 1.0f) * __builtin_amdgcn_rcpf(t + 1.0f);
}

// ---------------------------------------------------------------------------
// Main: one block per batch, 512 threads, 2048 sequential steps (x2 unroll).
// Round-7 kernel verbatim (e+=8 chunks, launch_bounds(512,2), PIN 80).
// ---------------------------------------------------------------------------
#define GA(T_RD, E) (*(const float*)((const char*)(T_RD) + cidx[E]))

#define ESN_STEP(T_RD, T_WR, RWR, SIDX)                                      \
  {                                                                          \
    float d0 = 0.f, d1 = 0.f, d2 = 0.f, d3 = 0.f;                            \
    _Pragma("unroll")                                                        \
    for (int e = 0; e < PAD; e += 8) {                                       \
      if (e < cw) {                                                          \
        d0 = fmaf(wval[e + 0], GA(T_RD, e + 0), d0);                         \
        d1 = fmaf(wval[e + 1], GA(T_RD, e + 1), d1);                         \
        d2 = fmaf(wval[e + 2], GA(T_RD, e + 2), d2);                         \
        d3 = fmaf(wval[e + 3], GA(T_RD, e + 3), d3);                         \
        d0 = fmaf(wval[e + 4], GA(T_RD, e + 4), d0);                         \
        d1 = fmaf(wval[e + 5], GA(T_RD, e + 5), d1);                         \
        d2 = fmaf(wval[e + 6], GA(T_RD, e + 6), d2);                         \
        d3 = fmaf(wval[e + 7], GA(T_RD, e + 7), d3);                         \
      }                                                                      \
    }                                                                        \
    float dot  = (d0 + d1) + (d2 + d3);                                      \
    float xp   = x_lds[SIDX] * w_ih;                                         \
    float dhdt = ((dot - h) + xp) + z_prev * w_zh;                           \
    float hn   = h + 0.1f * dhdt;                                            \
    float thn  = ftanh(hn);                                                  \
    T_WR[row] = thn;                                                         \
    oh[(SIDX) * NH + row] = hn;                                              \
    float pzs = wave_sum_lane63(thn * w_hz);                                 \
    if (lane == 63) red[RWR][wid] = pzs;                                     \
    asm volatile("s_waitcnt lgkmcnt(0)\n\ts_barrier" ::: "memory");          \
    float4 r0 = *(const float4*)&red[RWR][0];                                \
    float4 r1 = *(const float4*)&red[RWR][4];                                \
    float z = ((r0.x + r0.y) + (r0.z + r0.w)) + ((r1.x + r1.y) + (r1.z + r1.w)); \
    if (p == 0) oz[SIDX] = z;                                                \
    z_prev = z; h = hn;                                                      \
  }

__global__ __launch_bounds__(512, 2) void esn_steps(
    const float* __restrict__ x,   const float* __restrict__ h0,
    const float* __restrict__ Wih, const float* __restrict__ Whz,
    const float* __restrict__ Wzh, const float* __restrict__ vals,
    const unsigned* __restrict__ offs, const int* __restrict__ perm2,
    const int* __restrict__ cntw, float* __restrict__ out) {
  __shared__ float t_lds[2][NH];              // tanh(h), double-buffered
  __shared__ float x_lds[TT];                 // this batch's input row
  __shared__ __align__(16) float red[2][8];   // cross-wave partials for z

  const int p    = threadIdx.x;               // position owned
  const int b    = blockIdx.x;
  const int lane = p & 63;
  const int wid  = p >> 6;
  const int row  = perm2[p];                  // actual hidden unit

  float* t0 = t_lds[0];
  float* t1 = t_lds[1];

  for (int i = p; i < TT; i += NH) x_lds[i] = x[(size_t)b * TT + i];

  int cw = __builtin_amdgcn_readfirstlane((cntw[wid] + 7) & ~7);

  float    wval[PAD];
  unsigned cidx[PAD];
  #pragma unroll
  for (int e = 0; e < PAD; ++e) {
    wval[e] = vals[e * NH + p];
    cidx[e] = offs[e * NH + p] * 4u;
  }
  #pragma unroll
  for (int e = 0; e < PIN; ++e)
    asm volatile("" : "+v"(wval[e]), "+v"(cidx[e]));

  const float w_ih = Wih[row];
  const float w_hz = Whz[row];
  const float w_zh = Wzh[row];
  float h = h0[(size_t)b * NH + row];

  float* oz = out + (size_t)b * TT;                        // z region [B,T,1]
  float* oh = out + (size_t)BB * TT + (size_t)b * TT * NH; // h region [B,T,NH]

  float th0 = ftanh(h);
  t0[row] = th0;
  float pz = wave_sum_lane63(th0 * w_hz);
  if (lane == 63) red[0][wid] = pz;
  __syncthreads();
  float4 i0 = *(const float4*)&red[0][0];
  float4 i1 = *(const float4*)&red[0][4];
  float z_prev = ((i0.x + i0.y) + (i0.z + i0.w)) + ((i1.x + i1.y) + (i1.z + i1.w));

  for (int s = 0; s < TT; s += 2) {
    ESN_STEP(t0, t1, 1, s);
    ESN_STEP(t1, t0, 0, s + 1);
  }
}

// ---------------------------------------------------------------------------
extern "C" void kernel_launch(void* const* d_in, const int* in_sizes, int n_in,
                              void* d_out, int out_size, void* d_ws,
                              size_t ws_size, hipStream_t stream) {
  const float* x   = (const float*)d_in[0];
  const float* h0  = (const float*)d_in[1];
  const float* Wih = (const float*)d_in[2];
  const float* Whh = (const float*)d_in[3];
  const float* Whz = (const float*)d_in[4];
  const float* Wzh = (const float*)d_in[5];
  float* out = (float*)d_out;

  float*    vals  = (float*)d_ws;                    // PAD*NH f32 = 192 KB
  unsigned* offs  = (unsigned*)(vals + PAD * NH);    // PAD*NH u32 = 192 KB
  int*      nnz   = (int*)(offs + PAD * NH);         // NH
  int*      perm  = nnz + NH;                        // NH
  int*      perm2 = perm + NH;                       // NH
  int*      cntw  = perm2 + NH;                      // 8

  hipLaunchKernelGGL(count_nnz, dim3(NH / 8), dim3(512), 0, stream, Whh, nnz);
  hipLaunchKernelGGL(sort_rows, dim3(1), dim3(512), 0, stream, nnz, perm);
  hipLaunchKernelGGL(build_koenig, dim3(8), dim3(64), 0, stream,
                     Whh, perm, perm2, vals, offs, cntw);
  hipLaunchKernelGGL(esn_steps, dim3(BB), dim3(512), 0, stream,
                     x, h0, Wih, Whz, Wzh, vals, offs, perm2, cntw, out);
}